// Round 1
// baseline (3587.318 us; speedup 1.0000x reference)
//
#include <hip/hip_runtime.h>
#include <math.h>

// ResidualMP GNN inference, fp32 baseline.
// N=50000 nodes, E=800000 edges, D=MH=256, C=47, L=3.
//
// Pipeline per layer:
//   z = scatter_mean(x[src] -> dst)           (CSR gather, built once per call)
//   prop = x@Wl + z@Wr + bl + br              (dual GEMM, EPI=0)
//   h = prop@W1 + b1                          (EPI=0)
//   2x { t = affine(relu(h@Wa+ba)); h += t@Wb + bb }   (EPI=1 then EPI=2)
//   x = relu(l2normalize(h@W2 + b2))          (EPI=3)
// post: h = x@pW1 + pb1 (EPI=0); out = log_softmax(h@pW2 + pb2) (head kernel)

constexpr int DIM = 256;
constexpr int NL = 3;
constexpr int NCLS = 47;

__device__ __forceinline__ float4 ld4(const float* p) { return *(const float4*)p; }

// ---------------- CSR build ----------------

__global__ void hist_kernel(const int* __restrict__ ei, int* __restrict__ cnt, int E) {
    int g = blockIdx.x * blockDim.x + threadIdx.x;
    if (g < E) atomicAdd(&cnt[ei[E + g]], 1);   // dst = ei[1][e]
}

__global__ __launch_bounds__(1024) void scan_kernel(const int* __restrict__ cnt,
                                                    int* __restrict__ rowptr,
                                                    int* __restrict__ cursor,
                                                    float* __restrict__ invc, int n) {
    __shared__ int part[1024];
    int tid = threadIdx.x;
    int chunk = (n + 1023) / 1024;
    int b = tid * chunk;
    int e = min(b + chunk, n);
    int s = 0;
    for (int i = b; i < e; ++i) s += cnt[i];
    part[tid] = s;
    __syncthreads();
    for (int off = 1; off < 1024; off <<= 1) {
        int v = 0;
        if (tid >= off) v = part[tid - off];
        __syncthreads();
        part[tid] += v;
        __syncthreads();
    }
    int run = part[tid] - s;  // exclusive prefix for this chunk
    for (int i = b; i < e; ++i) {
        rowptr[i] = run;
        cursor[i] = run;
        int c = cnt[i];
        invc[i] = 1.0f / (float)(c > 0 ? c : 1);
        run += c;
    }
    if (tid == 1023) rowptr[n] = run;  // == E
}

__global__ void fill_kernel(const int* __restrict__ ei, int* __restrict__ cursor,
                            int* __restrict__ colb, int E) {
    int g = blockIdx.x * blockDim.x + threadIdx.x;
    if (g < E) {
        int s = ei[g];          // src = ei[0][e]
        int d = ei[E + g];      // dst
        int p = atomicAdd(&cursor[d], 1);
        colb[p] = s;
    }
}

// one wave per destination row: z[r] = (1/max(deg,1)) * sum_{p} x[col[p]]
__global__ __launch_bounds__(256) void gather_mean(const float* __restrict__ x,
                                                   const int* __restrict__ rowptr,
                                                   const int* __restrict__ colb,
                                                   const float* __restrict__ invc,
                                                   float* __restrict__ z, int n) {
    int gw = (blockIdx.x * 256 + threadIdx.x) >> 6;
    int lane = threadIdx.x & 63;
    int nw = (gridDim.x * 256) >> 6;
    for (int r = gw; r < n; r += nw) {
        int p0 = rowptr[r], p1 = rowptr[r + 1];
        float a0 = 0.f, a1 = 0.f, a2 = 0.f, a3 = 0.f;
        for (int p = p0; p < p1; ++p) {
            int s = colb[p];
            float4 v = ld4(&x[(size_t)s * DIM + lane * 4]);
            a0 += v.x; a1 += v.y; a2 += v.z; a3 += v.w;
        }
        float iv = invc[r];
        *(float4*)&z[(size_t)r * DIM + lane * 4] = make_float4(a0 * iv, a1 * iv, a2 * iv, a3 * iv);
    }
}

// ---------------- fp32 GEMM, K=256, ncols=256, full-width output tile ----------------
// BM=64 rows/block, 256 threads (4 waves), thread = 16 rows x 4 cols.
// EPI: 0 = C = A@W + bias1 (+bias2)
//      1 = C = gamma*bnscale*relu(A@W+bias1) + beta
//      2 = C += A@W + bias1
//      3 = C = relu(l2normalize_row(A@W + bias1))
// DUAL: adds second pass A2@W2 into the same accumulators (bias2 applies).
// In-place C == A (or A2) is safe: single column block -> each row range is
// read and written by exactly one block, all reads precede the epilogue.
template <int EPI, bool DUAL>
__global__ __launch_bounds__(256) void gemm_k256(
    const float* __restrict__ A1, const float* __restrict__ W1,
    const float* __restrict__ A2, const float* __restrict__ W2,
    const float* __restrict__ bias1, const float* __restrict__ bias2,
    const float* __restrict__ gamma, const float* __restrict__ beta,
    float bnscale, float* __restrict__ Cmat, int nrows) {
    __shared__ float sA[64 * 16];
    __shared__ float sB[16 * 256];
    const int tid = threadIdx.x;
    const int lane = tid & 63;
    const int wv = tid >> 6;
    const int row0 = blockIdx.x * 64;

    float acc[16][4];
#pragma unroll
    for (int i = 0; i < 16; ++i) {
        acc[i][0] = 0.f; acc[i][1] = 0.f; acc[i][2] = 0.f; acc[i][3] = 0.f;
    }

    const int arow = tid >> 2;            // 0..63
    const int acolo = (tid & 3) << 2;     // 0,4,8,12
    const bool arow_ok = (row0 + arow) < nrows;

    const int npass = DUAL ? 2 : 1;
    for (int pass = 0; pass < npass; ++pass) {
        const float* __restrict__ A = pass ? A2 : A1;
        const float* __restrict__ W = pass ? W2 : W1;
        for (int kt = 0; kt < 16; ++kt) {
            // stage A tile 64x16 (lane-contiguous LDS writes)
            float4 av = make_float4(0.f, 0.f, 0.f, 0.f);
            if (arow_ok) av = ld4(&A[(size_t)(row0 + arow) * DIM + kt * 16 + acolo]);
            *(float4*)&sA[tid * 4] = av;
            // stage B tile 16x256 (linear copy, coalesced + conflict-free)
#pragma unroll
            for (int q = 0; q < 4; ++q) {
                int o = q * 1024 + tid * 4;
                *(float4*)&sB[o] = ld4(&W[(size_t)kt * 4096 + o]);
            }
            __syncthreads();
#pragma unroll
            for (int kk4 = 0; kk4 < 4; ++kk4) {
                float4 b0 = *(const float4*)&sB[(kk4 * 4 + 0) * 256 + lane * 4];
                float4 b1 = *(const float4*)&sB[(kk4 * 4 + 1) * 256 + lane * 4];
                float4 b2 = *(const float4*)&sB[(kk4 * 4 + 2) * 256 + lane * 4];
                float4 b3 = *(const float4*)&sB[(kk4 * 4 + 3) * 256 + lane * 4];
#pragma unroll
                for (int i = 0; i < 16; ++i) {
                    float4 a = *(const float4*)&sA[(wv * 16 + i) * 16 + kk4 * 4];
                    acc[i][0] = fmaf(a.x, b0.x, acc[i][0]);
                    acc[i][0] = fmaf(a.y, b1.x, acc[i][0]);
                    acc[i][0] = fmaf(a.z, b2.x, acc[i][0]);
                    acc[i][0] = fmaf(a.w, b3.x, acc[i][0]);
                    acc[i][1] = fmaf(a.x, b0.y, acc[i][1]);
                    acc[i][1] = fmaf(a.y, b1.y, acc[i][1]);
                    acc[i][1] = fmaf(a.z, b2.y, acc[i][1]);
                    acc[i][1] = fmaf(a.w, b3.y, acc[i][1]);
                    acc[i][2] = fmaf(a.x, b0.z, acc[i][2]);
                    acc[i][2] = fmaf(a.y, b1.z, acc[i][2]);
                    acc[i][2] = fmaf(a.z, b2.z, acc[i][2]);
                    acc[i][2] = fmaf(a.w, b3.z, acc[i][2]);
                    acc[i][3] = fmaf(a.x, b0.w, acc[i][3]);
                    acc[i][3] = fmaf(a.y, b1.w, acc[i][3]);
                    acc[i][3] = fmaf(a.z, b2.w, acc[i][3]);
                    acc[i][3] = fmaf(a.w, b3.w, acc[i][3]);
                }
            }
            __syncthreads();
        }
    }

    // epilogue
    const int c0 = lane * 4;
    float4 bs = ld4(&bias1[c0]);
    if (bias2) {
        float4 b2v = ld4(&bias2[c0]);
        bs.x += b2v.x; bs.y += b2v.y; bs.z += b2v.z; bs.w += b2v.w;
    }
    float4 gm = make_float4(0.f, 0.f, 0.f, 0.f), bt = gm;
    if (EPI == 1) {
        gm = ld4(&gamma[c0]);
        bt = ld4(&beta[c0]);
        gm.x *= bnscale; gm.y *= bnscale; gm.z *= bnscale; gm.w *= bnscale;
    }
#pragma unroll
    for (int i = 0; i < 16; ++i) {
        int r = row0 + wv * 16 + i;
        float v0 = acc[i][0] + bs.x;
        float v1 = acc[i][1] + bs.y;
        float v2 = acc[i][2] + bs.z;
        float v3 = acc[i][3] + bs.w;
        if (EPI == 1) {
            v0 = fmaf(fmaxf(v0, 0.f), gm.x, bt.x);
            v1 = fmaf(fmaxf(v1, 0.f), gm.y, bt.y);
            v2 = fmaf(fmaxf(v2, 0.f), gm.z, bt.z);
            v3 = fmaf(fmaxf(v3, 0.f), gm.w, bt.w);
        }
        if (EPI == 3) {
            float sq = v0 * v0 + v1 * v1 + v2 * v2 + v3 * v3;
#pragma unroll
            for (int off = 32; off > 0; off >>= 1) sq += __shfl_xor(sq, off);
            float inv = 1.0f / fmaxf(sqrtf(sq), 1e-12f);
            v0 = fmaxf(v0 * inv, 0.f);
            v1 = fmaxf(v1 * inv, 0.f);
            v2 = fmaxf(v2 * inv, 0.f);
            v3 = fmaxf(v3 * inv, 0.f);
        }
        if (r < nrows) {
            float* cp = &Cmat[(size_t)r * DIM + c0];
            if (EPI == 2) {
                float4 old = *(const float4*)cp;
                v0 += old.x; v1 += old.y; v2 += old.z; v3 += old.w;
            }
            *(float4*)cp = make_float4(v0, v1, v2, v3);
        }
    }
}

// ---------------- head: logits = H@W2 + b2 ; log_softmax ----------------
__global__ __launch_bounds__(256) void head_kernel(const float* __restrict__ H,
                                                   const float* __restrict__ W,
                                                   const float* __restrict__ b,
                                                   float* __restrict__ out, int n) {
    __shared__ float sW[256 * NCLS];
    for (int idx = threadIdx.x; idx < 256 * NCLS; idx += 256) sW[idx] = W[idx];
    __syncthreads();
    int lane = threadIdx.x & 63;
    int gw = (blockIdx.x * 256 + threadIdx.x) >> 6;
    int nw = (gridDim.x * 256) >> 6;
    for (int r = gw; r < n; r += nw) {
        float acc = (lane < NCLS) ? b[lane] : 0.f;
        const float4* h4 = (const float4*)&H[(size_t)r * DIM];
        for (int j4 = 0; j4 < 64; ++j4) {
            float4 h = h4[j4];
            if (lane < NCLS) {
                acc = fmaf(h.x, sW[(j4 * 4 + 0) * NCLS + lane], acc);
                acc = fmaf(h.y, sW[(j4 * 4 + 1) * NCLS + lane], acc);
                acc = fmaf(h.z, sW[(j4 * 4 + 2) * NCLS + lane], acc);
                acc = fmaf(h.w, sW[(j4 * 4 + 3) * NCLS + lane], acc);
            }
        }
        float m = (lane < NCLS) ? acc : -INFINITY;
#pragma unroll
        for (int off = 32; off > 0; off >>= 1) m = fmaxf(m, __shfl_xor(m, off));
        float e = (lane < NCLS) ? expf(acc - m) : 0.f;
#pragma unroll
        for (int off = 32; off > 0; off >>= 1) e += __shfl_xor(e, off);
        float lse = m + logf(e);
        // recompute own exp argument: acc - lse
        if (lane < NCLS) out[(size_t)r * NCLS + lane] = acc - lse;
    }
}

// ---------------- launch ----------------

extern "C" void kernel_launch(void* const* d_in, const int* in_sizes, int n_in,
                              void* d_out, int out_size, void* d_ws, size_t ws_size,
                              hipStream_t stream) {
    const float* x_in = (const float*)d_in[0];
    const int* ei = (const int*)d_in[1];  // int32: JAX default (x64 disabled) downcasts int64
    const float* linlW = (const float*)d_in[2];
    const float* linlb = (const float*)d_in[3];
    const float* linrW = (const float*)d_in[4];
    const float* linrb = (const float*)d_in[5];
    const float* W1 = (const float*)d_in[6];
    const float* b1 = (const float*)d_in[7];
    const float* blkWa = (const float*)d_in[8];
    const float* blkba = (const float*)d_in[9];
    const float* blkg = (const float*)d_in[10];
    const float* blkbt = (const float*)d_in[11];
    const float* blkWb = (const float*)d_in[12];
    const float* blkbb = (const float*)d_in[13];
    const float* W2 = (const float*)d_in[14];
    const float* b2 = (const float*)d_in[15];
    const float* pW1 = (const float*)d_in[16];
    const float* pb1 = (const float*)d_in[17];
    const float* pW2 = (const float*)d_in[18];
    const float* pb2 = (const float*)d_in[19];

    const int n = in_sizes[0] / DIM;
    const int E = in_sizes[1] / 2;

    char* ws = (char*)d_ws;
    size_t off = 0;
    auto take = [&](size_t bytes) {
        void* p = ws + off;
        off += (bytes + 255) & ~(size_t)255;
        return p;
    };
    float* bufA = (float*)take((size_t)n * DIM * 4);  // x (next layer)
    float* bufB = (float*)take((size_t)n * DIM * 4);  // z / prop / t / post-h
    float* bufD = (float*)take((size_t)n * DIM * 4);  // h
    int* cnt = (int*)take((size_t)n * 4);
    int* rowptr = (int*)take((size_t)(n + 1) * 4);
    int* cursor = (int*)take((size_t)n * 4);
    float* invc = (float*)take((size_t)n * 4);
    int* colb = (int*)take((size_t)E * 4);
    (void)ws_size; (void)n_in; (void)out_size;

    const float bnscale = 0.999995000037f;  // 1/sqrt(1 + 1e-5)

    // CSR build (edge list identical across layers -> build once per call)
    hipMemsetAsync(cnt, 0, (size_t)n * 4, stream);
    hist_kernel<<<(E + 255) / 256, 256, 0, stream>>>(ei, cnt, E);
    scan_kernel<<<1, 1024, 0, stream>>>(cnt, rowptr, cursor, invc, n);
    fill_kernel<<<(E + 255) / 256, 256, 0, stream>>>(ei, cursor, colb, E);

    const int gblocks = (n + 63) / 64;
    const float* xcur = x_in;
    for (int i = 0; i < NL; ++i) {
        gather_mean<<<(n + 3) / 4, 256, 0, stream>>>(xcur, rowptr, colb, invc, bufB, n);
        // prop = x@Wl + z@Wr + bl + br   (in-place over z in bufB: safe, see kernel)
        gemm_k256<0, true><<<gblocks, 256, 0, stream>>>(
            xcur, linlW + (size_t)i * 65536, bufB, linrW + (size_t)i * 65536,
            linlb + i * 256, linrb + i * 256, nullptr, nullptr, 0.f, bufB, n);
        // h = prop@W1 + b1
        gemm_k256<0, false><<<gblocks, 256, 0, stream>>>(
            bufB, W1 + (size_t)i * 65536, nullptr, nullptr, b1 + i * 256, nullptr,
            nullptr, nullptr, 0.f, bufD, n);
        for (int j = 0; j < 2; ++j) {
            size_t wo = (size_t)i * 2 + j;
            gemm_k256<1, false><<<gblocks, 256, 0, stream>>>(
                bufD, blkWa + wo * 65536, nullptr, nullptr, blkba + wo * 256, nullptr,
                blkg + wo * 256, blkbt + wo * 256, bnscale, bufB, n);
            gemm_k256<2, false><<<gblocks, 256, 0, stream>>>(
                bufB, blkWb + wo * 65536, nullptr, nullptr, blkbb + wo * 256, nullptr,
                nullptr, nullptr, 0.f, bufD, n);
        }
        // x = relu(normalize(h@W2 + b2))
        gemm_k256<3, false><<<gblocks, 256, 0, stream>>>(
            bufD, W2 + (size_t)i * 65536, nullptr, nullptr, b2 + i * 256, nullptr,
            nullptr, nullptr, 0.f, bufA, n);
        xcur = bufA;
    }
    // post: h = x@pW1 + pb1
    gemm_k256<0, false><<<gblocks, 256, 0, stream>>>(
        bufA, pW1, nullptr, nullptr, pb1, nullptr, nullptr, nullptr, 0.f, bufB, n);
    head_kernel<<<1024, 256, 0, stream>>>(bufB, pW2, pb2, (float*)d_out, n);
}

// Round 2
// 2173.310 us; speedup vs baseline: 1.6506x; 1.6506x over previous
//
#include <hip/hip_runtime.h>
#include <math.h>

// ResidualMP GNN inference. GEMMs on MFMA (split bf16 hi/lo for ~fp32 accuracy).
// N=50000, E=800000, D=MH=256, C=47, L=3.

constexpr int DIM = 256;
constexpr int NL = 3;
constexpr int NCLS = 47;

typedef short short8 __attribute__((ext_vector_type(8)));
typedef float f32x4 __attribute__((ext_vector_type(4)));

__device__ __forceinline__ float4 ld4(const float* p) { return *(const float4*)p; }

// round-to-nearest-even f32 -> bf16 (bit pattern), plus residual
__device__ __forceinline__ void split_bf16(float a, short& hi, short& lo) {
    unsigned u = __float_as_uint(a);
    unsigned r = (u + 0x7fffu + ((u >> 16) & 1u)) & 0xffff0000u;
    hi = (short)(r >> 16);
    float f = a - __uint_as_float(r);   // exact (Sterbenz)
    unsigned u2 = __float_as_uint(f);
    lo = (short)((u2 + 0x7fffu + ((u2 >> 16) & 1u)) >> 16);
}

// ---------------- CSR build ----------------

__global__ void hist_kernel(const int* __restrict__ ei, int* __restrict__ cnt, int E) {
    int g = blockIdx.x * blockDim.x + threadIdx.x;
    if (g < E) atomicAdd(&cnt[ei[E + g]], 1);   // dst = ei[1][e]
}

__global__ __launch_bounds__(1024) void scan_kernel(const int* __restrict__ cnt,
                                                    int* __restrict__ rowptr,
                                                    int* __restrict__ cursor,
                                                    float* __restrict__ invc, int n) {
    __shared__ int part[1024];
    int tid = threadIdx.x;
    int chunk = (n + 1023) / 1024;
    int b = tid * chunk;
    int e = min(b + chunk, n);
    int s = 0;
    for (int i = b; i < e; ++i) s += cnt[i];
    part[tid] = s;
    __syncthreads();
    for (int off = 1; off < 1024; off <<= 1) {
        int v = 0;
        if (tid >= off) v = part[tid - off];
        __syncthreads();
        part[tid] += v;
        __syncthreads();
    }
    int run = part[tid] - s;
    for (int i = b; i < e; ++i) {
        rowptr[i] = run;
        cursor[i] = run;
        int c = cnt[i];
        invc[i] = 1.0f / (float)(c > 0 ? c : 1);
        run += c;
    }
    if (tid == 1023) rowptr[n] = run;
}

__global__ void fill_kernel(const int* __restrict__ ei, int* __restrict__ cursor,
                            int* __restrict__ colb, int E) {
    int g = blockIdx.x * blockDim.x + threadIdx.x;
    if (g < E) {
        int s = ei[g];
        int d = ei[E + g];
        int p = atomicAdd(&cursor[d], 1);
        colb[p] = s;
    }
}

// one wave per destination row: z[r] = (1/max(deg,1)) * sum_p x[col[p]]
__global__ __launch_bounds__(256) void gather_mean(const float* __restrict__ x,
                                                   const int* __restrict__ rowptr,
                                                   const int* __restrict__ colb,
                                                   const float* __restrict__ invc,
                                                   float* __restrict__ z, int n) {
    int gw = (blockIdx.x * 256 + threadIdx.x) >> 6;
    int lane = threadIdx.x & 63;
    int nw = (gridDim.x * 256) >> 6;
    for (int r = gw; r < n; r += nw) {
        int p0 = rowptr[r], p1 = rowptr[r + 1];
        float a0 = 0.f, a1 = 0.f, a2 = 0.f, a3 = 0.f;
        for (int p = p0; p < p1; ++p) {
            int s = colb[p];
            float4 v = ld4(&x[(size_t)s * DIM + lane * 4]);
            a0 += v.x; a1 += v.y; a2 += v.z; a3 += v.w;
        }
        float iv = invc[r];
        *(float4*)&z[(size_t)r * DIM + lane * 4] = make_float4(a0 * iv, a1 * iv, a2 * iv, a3 * iv);
    }
}

// ---------------- weight conversion: fp32 [256][256] -> frag-ordered hi/lo bf16 ----------------
// Per matrix: 8 ksteps x 16 coltiles x 64 lanes, 8 bf16 per entry.
// Entry e=(kt*16+ct)*64+lane holds B[k = kt*32+(lane>>4)*8+j][col = ct*16+(lane&15)], j=0..7.
// hi plane at m*131072 shorts, lo plane at +65536.
__global__ __launch_bounds__(256) void conv_w_kernel(const float* __restrict__ W,
                                                     short* __restrict__ out, int nmat) {
    int idx = blockIdx.x * 256 + threadIdx.x;
    if (idx >= nmat * 8192) return;
    int m = idx >> 13;
    int e = idx & 8191;
    int kt = e >> 10;
    int ct = (e >> 6) & 15;
    int lane = e & 63;
    int k0 = kt * 32 + ((lane >> 4) << 3);
    int col = ct * 16 + (lane & 15);
    const float* Wm = W + (size_t)m * 65536;
    short8 hi, lo;
#pragma unroll
    for (int j = 0; j < 8; ++j) {
        short h, l;
        split_bf16(Wm[(size_t)(k0 + j) * 256 + col], h, l);
        hi[j] = h; lo[j] = l;
    }
    short* hp = out + (size_t)m * 131072 + (size_t)e * 8;
    *(short8*)hp = hi;
    *(short8*)(hp + 65536) = lo;
}

// ---------------- MFMA GEMM: [nrows,256] @ [256,256], full-width tile ----------------
// Block: 64 rows, 4 waves. Wave (wm=w&1, wn=w>>1): rows wm*32+[0,32), cols wn*128+[0,128).
// Per wave: M_rep=2, N_rep=8 frags of 16x16; 3 MFMAs (hh,hl,lh) per frag pair.
// EPI: 0 = bias ; 1 = gamma*bn*relu(+bias)+beta ; 2 = C += ; 3 = relu(l2norm(+bias))
template <int EPI, bool DUAL>
__global__ __launch_bounds__(256) void gemm_mfma(
    const float* __restrict__ A1, const short* __restrict__ W1f,
    const float* __restrict__ A2, const short* __restrict__ W2f,
    const float* __restrict__ bias1, const float* __restrict__ bias2,
    const float* __restrict__ gamma, const float* __restrict__ beta,
    float bnscale, float* __restrict__ Cmat, int nrows) {
    __shared__ float snorm[2][64];
    const int tid = threadIdx.x;
    const int lane = tid & 63;
    const int wv = tid >> 6;
    const int wm = wv & 1;
    const int wn = wv >> 1;
    const int row0 = blockIdx.x * 64;
    const int lr = lane & 15;             // row-in-frag (A) / col-in-frag (B,D)
    const int lk = (lane >> 4) << 3;      // k offset within 32

    f32x4 acc[2][8];
#pragma unroll
    for (int mi = 0; mi < 2; ++mi)
#pragma unroll
        for (int n = 0; n < 8; ++n) acc[mi][n] = (f32x4){0.f, 0.f, 0.f, 0.f};

    const int npass = DUAL ? 2 : 1;
    for (int pass = 0; pass < npass; ++pass) {
        const float* __restrict__ A = pass ? A2 : A1;
        const short* __restrict__ Wf = pass ? W2f : W1f;
#pragma unroll
        for (int kt = 0; kt < 8; ++kt) {
            short8 ahi[2], alo[2];
#pragma unroll
            for (int mi = 0; mi < 2; ++mi) {
                int r = row0 + wm * 32 + mi * 16 + lr;
                float4 u0 = make_float4(0.f, 0.f, 0.f, 0.f), u1 = u0;
                if (r < nrows) {
                    const float* ap = A + (size_t)r * DIM + kt * 32 + lk;
                    u0 = ld4(ap);
                    u1 = ld4(ap + 4);
                }
                float v[8] = {u0.x, u0.y, u0.z, u0.w, u1.x, u1.y, u1.z, u1.w};
#pragma unroll
                for (int j = 0; j < 8; ++j) {
                    short h, l;
                    split_bf16(v[j], h, l);
                    ahi[mi][j] = h; alo[mi][j] = l;
                }
            }
            const short* wb = Wf + (((size_t)(kt * 16 + wn * 8) * 64 + lane) << 3);
#pragma unroll
            for (int n = 0; n < 8; ++n) {
                short8 bhi = *(const short8*)(wb + n * 512);
                short8 blo = *(const short8*)(wb + n * 512 + 65536);
#pragma unroll
                for (int mi = 0; mi < 2; ++mi) {
                    acc[mi][n] = __builtin_amdgcn_mfma_f32_16x16x32_bf16(ahi[mi], bhi, acc[mi][n], 0, 0, 0);
                    acc[mi][n] = __builtin_amdgcn_mfma_f32_16x16x32_bf16(ahi[mi], blo, acc[mi][n], 0, 0, 0);
                    acc[mi][n] = __builtin_amdgcn_mfma_f32_16x16x32_bf16(alo[mi], bhi, acc[mi][n], 0, 0, 0);
                }
            }
        }
    }

    // ---------------- epilogue ----------------
    // D frag (mi,n): col = (wn*8+n)*16 + lr ; row = row0 + wm*32 + mi*16 + (lane>>4)*4 + reg
    float bias[8], gm[8], bt[8];
#pragma unroll
    for (int n = 0; n < 8; ++n) {
        int coln = wn * 128 + n * 16 + lr;
        bias[n] = bias1[coln] + (bias2 ? bias2[coln] : 0.f);
        if (EPI == 1) {
            gm[n] = gamma[coln] * bnscale;
            bt[n] = beta[coln];
        }
    }
    const int rbase = (lane >> 4) << 2;  // 0,4,8,12

    if (EPI == 3) {
        // add bias in place, accumulate row sum-of-squares
#pragma unroll
        for (int mi = 0; mi < 2; ++mi) {
            float sq[4] = {0.f, 0.f, 0.f, 0.f};
#pragma unroll
            for (int n = 0; n < 8; ++n) {
#pragma unroll
                for (int reg = 0; reg < 4; ++reg) {
                    float v = acc[mi][n][reg] + bias[n];
                    acc[mi][n][reg] = v;
                    sq[reg] = fmaf(v, v, sq[reg]);
                }
            }
#pragma unroll
            for (int reg = 0; reg < 4; ++reg) {
                float s = sq[reg];
                s += __shfl_xor(s, 1);
                s += __shfl_xor(s, 2);
                s += __shfl_xor(s, 4);
                s += __shfl_xor(s, 8);
                if (lr == 0) snorm[wn][wm * 32 + mi * 16 + rbase + reg] = s;
            }
        }
        __syncthreads();
#pragma unroll
        for (int mi = 0; mi < 2; ++mi) {
#pragma unroll
            for (int reg = 0; reg < 4; ++reg) {
                int ridx = wm * 32 + mi * 16 + rbase + reg;
                int r = row0 + ridx;
                float s = snorm[0][ridx] + snorm[1][ridx];
                float inv = 1.0f / fmaxf(sqrtf(s), 1e-12f);
                if (r < nrows) {
#pragma unroll
                    for (int n = 0; n < 8; ++n) {
                        int col = wn * 128 + n * 16 + lr;
                        Cmat[(size_t)r * DIM + col] = fmaxf(acc[mi][n][reg] * inv, 0.f);
                    }
                }
            }
        }
        return;
    }

#pragma unroll
    for (int mi = 0; mi < 2; ++mi) {
#pragma unroll
        for (int reg = 0; reg < 4; ++reg) {
            int r = row0 + wm * 32 + mi * 16 + rbase + reg;
            if (r < nrows) {
#pragma unroll
                for (int n = 0; n < 8; ++n) {
                    int col = wn * 128 + n * 16 + lr;
                    float v = acc[mi][n][reg] + bias[n];
                    if (EPI == 1) v = fmaf(fmaxf(v, 0.f), gm[n], bt[n]);
                    float* cp = &Cmat[(size_t)r * DIM + col];
                    if (EPI == 2) v += *cp;
                    *cp = v;
                }
            }
        }
    }
}

// ---------------- head: logits = H@W2 + b2 ; log_softmax ----------------
__global__ __launch_bounds__(256) void head_kernel(const float* __restrict__ H,
                                                   const float* __restrict__ W,
                                                   const float* __restrict__ b,
                                                   float* __restrict__ out, int n) {
    __shared__ float sW[256 * NCLS];
    for (int idx = threadIdx.x; idx < 256 * NCLS; idx += 256) sW[idx] = W[idx];
    __syncthreads();
    int lane = threadIdx.x & 63;
    int gw = (blockIdx.x * 256 + threadIdx.x) >> 6;
    int nw = (gridDim.x * 256) >> 6;
    for (int r = gw; r < n; r += nw) {
        float acc = (lane < NCLS) ? b[lane] : 0.f;
        const float4* h4 = (const float4*)&H[(size_t)r * DIM];
        for (int j4 = 0; j4 < 64; ++j4) {
            float4 h = h4[j4];
            if (lane < NCLS) {
                acc = fmaf(h.x, sW[(j4 * 4 + 0) * NCLS + lane], acc);
                acc = fmaf(h.y, sW[(j4 * 4 + 1) * NCLS + lane], acc);
                acc = fmaf(h.z, sW[(j4 * 4 + 2) * NCLS + lane], acc);
                acc = fmaf(h.w, sW[(j4 * 4 + 3) * NCLS + lane], acc);
            }
        }
        float m = (lane < NCLS) ? acc : -INFINITY;
#pragma unroll
        for (int off = 32; off > 0; off >>= 1) m = fmaxf(m, __shfl_xor(m, off));
        float e = (lane < NCLS) ? expf(acc - m) : 0.f;
#pragma unroll
        for (int off = 32; off > 0; off >>= 1) e += __shfl_xor(e, off);
        float lse = m + logf(e);
        if (lane < NCLS) out[(size_t)r * NCLS + lane] = acc - lse;
    }
}

// ---------------- launch ----------------

extern "C" void kernel_launch(void* const* d_in, const int* in_sizes, int n_in,
                              void* d_out, int out_size, void* d_ws, size_t ws_size,
                              hipStream_t stream) {
    const float* x_in = (const float*)d_in[0];
    const int* ei = (const int*)d_in[1];
    const float* linlW = (const float*)d_in[2];
    const float* linlb = (const float*)d_in[3];
    const float* linrW = (const float*)d_in[4];
    const float* linrb = (const float*)d_in[5];
    const float* W1 = (const float*)d_in[6];
    const float* b1 = (const float*)d_in[7];
    const float* blkWa = (const float*)d_in[8];
    const float* blkba = (const float*)d_in[9];
    const float* blkg = (const float*)d_in[10];
    const float* blkbt = (const float*)d_in[11];
    const float* blkWb = (const float*)d_in[12];
    const float* blkbb = (const float*)d_in[13];
    const float* W2 = (const float*)d_in[14];
    const float* b2 = (const float*)d_in[15];
    const float* pW1 = (const float*)d_in[16];
    const float* pb1 = (const float*)d_in[17];
    const float* pW2 = (const float*)d_in[18];
    const float* pb2 = (const float*)d_in[19];

    const int n = in_sizes[0] / DIM;
    const int E = in_sizes[1] / 2;

    char* ws = (char*)d_ws;
    size_t off = 0;
    auto take = [&](size_t bytes) {
        void* p = ws + off;
        off += (bytes + 255) & ~(size_t)255;
        return p;
    };
    float* bufA = (float*)take((size_t)n * DIM * 4);
    float* bufB = (float*)take((size_t)n * DIM * 4);
    float* bufD = (float*)take((size_t)n * DIM * 4);
    int* cnt = (int*)take((size_t)n * 4);
    int* rowptr = (int*)take((size_t)(n + 1) * 4);
    int* cursor = (int*)take((size_t)n * 4);
    float* invc = (float*)take((size_t)n * 4);
    int* colb = (int*)take((size_t)E * 4);
    short* wbuf = (short*)take((size_t)25 * 131072 * 2);  // 25 matrices, hi+lo frag planes
    (void)ws_size; (void)n_in; (void)out_size;

    const float bnscale = 0.999995000037f;  // 1/sqrt(1 + 1e-5)

    // frag-plane bases (in shorts): matrix order below
    auto WF = [&](int m) { return wbuf + (size_t)m * 131072; };
    // 0..2 linl | 3..5 linr | 6..8 W1 | 9..14 blkWa | 15..20 blkWb | 21..23 W2 | 24 postW1
    conv_w_kernel<<<3 * 32, 256, 0, stream>>>(linlW, WF(0), 3);
    conv_w_kernel<<<3 * 32, 256, 0, stream>>>(linrW, WF(3), 3);
    conv_w_kernel<<<3 * 32, 256, 0, stream>>>(W1, WF(6), 3);
    conv_w_kernel<<<6 * 32, 256, 0, stream>>>(blkWa, WF(9), 6);
    conv_w_kernel<<<6 * 32, 256, 0, stream>>>(blkWb, WF(15), 6);
    conv_w_kernel<<<3 * 32, 256, 0, stream>>>(W2, WF(21), 3);
    conv_w_kernel<<<1 * 32, 256, 0, stream>>>(pW1, WF(24), 1);

    // CSR build
    hipMemsetAsync(cnt, 0, (size_t)n * 4, stream);
    hist_kernel<<<(E + 255) / 256, 256, 0, stream>>>(ei, cnt, E);
    scan_kernel<<<1, 1024, 0, stream>>>(cnt, rowptr, cursor, invc, n);
    fill_kernel<<<(E + 255) / 256, 256, 0, stream>>>(ei, cursor, colb, E);

    const int gblocks = (n + 63) / 64;
    const float* xcur = x_in;
    for (int i = 0; i < NL; ++i) {
        gather_mean<<<(n + 3) / 4, 256, 0, stream>>>(xcur, rowptr, colb, invc, bufB, n);
        // prop = x@Wl + z@Wr + bl + br   (in-place over z: block reads only its own rows)
        gemm_mfma<0, true><<<gblocks, 256, 0, stream>>>(
            xcur, WF(0 + i), bufB, WF(3 + i),
            linlb + i * 256, linrb + i * 256, nullptr, nullptr, 0.f, bufB, n);
        // h = prop@W1 + b1
        gemm_mfma<0, false><<<gblocks, 256, 0, stream>>>(
            bufB, WF(6 + i), nullptr, nullptr, b1 + i * 256, nullptr,
            nullptr, nullptr, 0.f, bufD, n);
        for (int j = 0; j < 2; ++j) {
            int wo = i * 2 + j;
            gemm_mfma<1, false><<<gblocks, 256, 0, stream>>>(
                bufD, WF(9 + wo), nullptr, nullptr, blkba + wo * 256, nullptr,
                blkg + wo * 256, blkbt + wo * 256, bnscale, bufB, n);
            gemm_mfma<2, false><<<gblocks, 256, 0, stream>>>(
                bufB, WF(15 + wo), nullptr, nullptr, blkbb + wo * 256, nullptr,
                nullptr, nullptr, 0.f, bufD, n);
        }
        // x = relu(normalize(h@W2 + b2))
        gemm_mfma<3, false><<<gblocks, 256, 0, stream>>>(
            bufD, WF(21 + i), nullptr, nullptr, b2 + i * 256, nullptr,
            nullptr, nullptr, 0.f, bufA, n);
        xcur = bufA;
    }
    // post: h = x@pW1 + pb1
    gemm_mfma<0, false><<<gblocks, 256, 0, stream>>>(
        bufA, WF(24), nullptr, nullptr, pb1, nullptr, nullptr, nullptr, 0.f, bufB, n);
    head_kernel<<<1024, 256, 0, stream>>>(bufB, pW2, pb2, (float*)d_out, n);
}

// Round 3
// 2020.534 us; speedup vs baseline: 1.7754x; 1.0756x over previous
//
#include <hip/hip_runtime.h>
#include <hip/hip_bf16.h>
#include <math.h>

// ResidualMP GNN inference. GEMMs on MFMA (split bf16 hi/lo for ~fp32 accuracy).
// N=50000, E=800000, D=MH=256, C=47, L=3.

constexpr int DIM = 256;
constexpr int NL = 3;
constexpr int NCLS = 47;

typedef short short8 __attribute__((ext_vector_type(8)));
typedef float f32x4 __attribute__((ext_vector_type(4)));

__device__ __forceinline__ float4 ld4(const float* p) { return *(const float4*)p; }

// scalar split (conversion kernels only)
__device__ __forceinline__ void split_bf16(float a, short& hi, short& lo) {
    unsigned u = __float_as_uint(a);
    unsigned r = (u + 0x7fffu + ((u >> 16) & 1u)) & 0xffff0000u;
    hi = (short)(r >> 16);
    float f = a - __uint_as_float(r);   // exact (Sterbenz)
    unsigned u2 = __float_as_uint(f);
    lo = (short)((u2 + 0x7fffu + ((u2 >> 16) & 1u)) >> 16);
}

// fast 8-wide split: v_cvt_pk_bf16_f32 pairs (compiler emits cvt_pk), residual exact
__device__ __forceinline__ void split8(const float4& u0, const float4& u1,
                                       short8& hi, short8& lo) {
    union { unsigned w[4]; short8 s; } H, L;
    float va[8] = {u0.x, u0.y, u0.z, u0.w, u1.x, u1.y, u1.z, u1.w};
#pragma unroll
    for (int p = 0; p < 4; ++p) {
        float a = va[2 * p], b = va[2 * p + 1];
        __hip_bfloat162 h2 = __float22bfloat162_rn(make_float2(a, b));
        float ra = a - __bfloat162float(h2.x);
        float rb = b - __bfloat162float(h2.y);
        __hip_bfloat162 l2 = __float22bfloat162_rn(make_float2(ra, rb));
        H.w[p] = *reinterpret_cast<unsigned*>(&h2);
        L.w[p] = *reinterpret_cast<unsigned*>(&l2);
    }
    hi = H.s; lo = L.s;
}

// ---------------- CSR build ----------------

__global__ void hist_kernel(const int* __restrict__ ei, int* __restrict__ cnt, int E) {
    int g = blockIdx.x * blockDim.x + threadIdx.x;
    if (g < E) atomicAdd(&cnt[ei[E + g]], 1);   // dst = ei[1][e]
}

__global__ __launch_bounds__(1024) void scan_kernel(const int* __restrict__ cnt,
                                                    int* __restrict__ rowptr,
                                                    int* __restrict__ cursor,
                                                    float* __restrict__ invc, int n) {
    __shared__ int part[1024];
    int tid = threadIdx.x;
    int chunk = (n + 1023) / 1024;
    int b = tid * chunk;
    int e = min(b + chunk, n);
    int s = 0;
    for (int i = b; i < e; ++i) s += cnt[i];
    part[tid] = s;
    __syncthreads();
    for (int off = 1; off < 1024; off <<= 1) {
        int v = 0;
        if (tid >= off) v = part[tid - off];
        __syncthreads();
        part[tid] += v;
        __syncthreads();
    }
    int run = part[tid] - s;
    for (int i = b; i < e; ++i) {
        rowptr[i] = run;
        cursor[i] = run;
        int c = cnt[i];
        invc[i] = 1.0f / (float)(c > 0 ? c : 1);
        run += c;
    }
    if (tid == 1023) rowptr[n] = run;
}

__global__ void fill_kernel(const int* __restrict__ ei, int* __restrict__ cursor,
                            int* __restrict__ colb, int E) {
    int g = blockIdx.x * blockDim.x + threadIdx.x;
    if (g < E) {
        int s = ei[g];
        int d = ei[E + g];
        int p = atomicAdd(&cursor[d], 1);
        colb[p] = s;
    }
}

// one wave per destination row: z[r] = (1/max(deg,1)) * sum_p x[col[p]]
__global__ __launch_bounds__(256) void gather_mean(const float* __restrict__ x,
                                                   const int* __restrict__ rowptr,
                                                   const int* __restrict__ colb,
                                                   const float* __restrict__ invc,
                                                   float* __restrict__ z, int n) {
    int gw = (blockIdx.x * 256 + threadIdx.x) >> 6;
    int lane = threadIdx.x & 63;
    int nw = (gridDim.x * 256) >> 6;
    for (int r = gw; r < n; r += nw) {
        int p0 = rowptr[r], p1 = rowptr[r + 1];
        float a0 = 0.f, a1 = 0.f, a2 = 0.f, a3 = 0.f;
        for (int p = p0; p < p1; ++p) {
            int s = colb[p];
            float4 v = ld4(&x[(size_t)s * DIM + lane * 4]);
            a0 += v.x; a1 += v.y; a2 += v.z; a3 += v.w;
        }
        float iv = invc[r];
        *(float4*)&z[(size_t)r * DIM + lane * 4] = make_float4(a0 * iv, a1 * iv, a2 * iv, a3 * iv);
    }
}

// ---------------- weight conversion: fp32 [256][256] -> frag-ordered hi/lo bf16 ----------------
// Entry e=(kt*16+ct)*64+lane holds B[k = kt*32+(lane>>4)*8+j][col = ct*16+(lane&15)], j=0..7.
__global__ __launch_bounds__(256) void conv_w_kernel(const float* __restrict__ W,
                                                     short* __restrict__ out, int nmat) {
    int idx = blockIdx.x * 256 + threadIdx.x;
    if (idx >= nmat * 8192) return;
    int m = idx >> 13;
    int e = idx & 8191;
    int kt = e >> 10;
    int ct = (e >> 6) & 15;
    int lane = e & 63;
    int k0 = kt * 32 + ((lane >> 4) << 3);
    int col = ct * 16 + (lane & 15);
    const float* Wm = W + (size_t)m * 65536;
    short8 hi, lo;
#pragma unroll
    for (int j = 0; j < 8; ++j) {
        short h, l;
        split_bf16(Wm[(size_t)(k0 + j) * 256 + col], h, l);
        hi[j] = h; lo[j] = l;
    }
    short* hp = out + (size_t)m * 131072 + (size_t)e * 8;
    *(short8*)hp = hi;
    *(short8*)(hp + 65536) = lo;
}

// post_W2 [256][47] -> frag planes padded to 64 cols: 8 kt x 4 ct x 64 lanes.
// hi plane 16384 shorts, lo plane at +16384.
__global__ __launch_bounds__(256) void conv_w2_kernel(const float* __restrict__ W,
                                                      short* __restrict__ out) {
    int e = blockIdx.x * 256 + threadIdx.x;
    if (e >= 2048) return;
    int kt = e >> 8;
    int ct = (e >> 6) & 3;
    int lane = e & 63;
    int k0 = kt * 32 + ((lane >> 4) << 3);
    int col = ct * 16 + (lane & 15);
    short8 hi, lo;
#pragma unroll
    for (int j = 0; j < 8; ++j) {
        float v = (col < NCLS) ? W[(size_t)(k0 + j) * NCLS + col] : 0.f;
        short h, l;
        split_bf16(v, h, l);
        hi[j] = h; lo[j] = l;
    }
    short* hp = out + (size_t)e * 8;
    *(short8*)hp = hi;
    *(short8*)(hp + 16384) = lo;
}

// ---------------- MFMA GEMM: [nrows,256] @ [256,256], full-width tile ----------------
// Block: 64 rows, 4 waves. Wave (wm=w&1, wn=w>>1): rows wm*32+[0,32), cols wn*128+[0,128).
// EPI: 0 = bias ; 1 = gamma*bn*relu(+bias)+beta ; 2 = C += ; 3 = relu(l2norm(+bias))
template <int EPI, bool DUAL>
__global__ __launch_bounds__(256) void gemm_mfma(
    const float* __restrict__ A1, const short* __restrict__ W1f,
    const float* __restrict__ A2, const short* __restrict__ W2f,
    const float* __restrict__ bias1, const float* __restrict__ bias2,
    const float* __restrict__ gamma, const float* __restrict__ beta,
    float bnscale, float* __restrict__ Cmat, int nrows) {
    __shared__ float snorm[2][64];
    const int tid = threadIdx.x;
    const int lane = tid & 63;
    const int wv = tid >> 6;
    const int wm = wv & 1;
    const int wn = wv >> 1;
    const int row0 = blockIdx.x * 64;
    const int lr = lane & 15;
    const int lk = (lane >> 4) << 3;

    f32x4 acc[2][8];
#pragma unroll
    for (int mi = 0; mi < 2; ++mi)
#pragma unroll
        for (int n = 0; n < 8; ++n) acc[mi][n] = (f32x4){0.f, 0.f, 0.f, 0.f};

    const int npass = DUAL ? 2 : 1;
    for (int pass = 0; pass < npass; ++pass) {
        const float* __restrict__ A = pass ? A2 : A1;
        const short* __restrict__ Wf = pass ? W2f : W1f;
#pragma unroll
        for (int kt = 0; kt < 8; ++kt) {
            short8 ahi[2], alo[2];
#pragma unroll
            for (int mi = 0; mi < 2; ++mi) {
                int r = row0 + wm * 32 + mi * 16 + lr;
                float4 u0 = make_float4(0.f, 0.f, 0.f, 0.f), u1 = u0;
                if (r < nrows) {
                    const float* ap = A + (size_t)r * DIM + kt * 32 + lk;
                    u0 = ld4(ap);
                    u1 = ld4(ap + 4);
                }
                split8(u0, u1, ahi[mi], alo[mi]);
            }
            const short* wb = Wf + (((size_t)(kt * 16 + wn * 8) * 64 + lane) << 3);
#pragma unroll
            for (int n = 0; n < 8; ++n) {
                short8 bhi = *(const short8*)(wb + n * 512);
                short8 blo = *(const short8*)(wb + n * 512 + 65536);
#pragma unroll
                for (int mi = 0; mi < 2; ++mi) {
                    acc[mi][n] = __builtin_amdgcn_mfma_f32_16x16x32_bf16(ahi[mi], bhi, acc[mi][n], 0, 0, 0);
                    acc[mi][n] = __builtin_amdgcn_mfma_f32_16x16x32_bf16(ahi[mi], blo, acc[mi][n], 0, 0, 0);
                    acc[mi][n] = __builtin_amdgcn_mfma_f32_16x16x32_bf16(alo[mi], bhi, acc[mi][n], 0, 0, 0);
                }
            }
        }
    }

    // epilogue: D frag (mi,n): col = wn*128+n*16+lr ; row = row0+wm*32+mi*16+(lane>>4)*4+reg
    float bias[8], gm[8], bt[8];
#pragma unroll
    for (int n = 0; n < 8; ++n) {
        int coln = wn * 128 + n * 16 + lr;
        bias[n] = bias1[coln] + (bias2 ? bias2[coln] : 0.f);
        if (EPI == 1) {
            gm[n] = gamma[coln] * bnscale;
            bt[n] = beta[coln];
        }
    }
    const int rbase = (lane >> 4) << 2;

    if (EPI == 3) {
#pragma unroll
        for (int mi = 0; mi < 2; ++mi) {
            float sq[4] = {0.f, 0.f, 0.f, 0.f};
#pragma unroll
            for (int n = 0; n < 8; ++n) {
#pragma unroll
                for (int reg = 0; reg < 4; ++reg) {
                    float v = acc[mi][n][reg] + bias[n];
                    acc[mi][n][reg] = v;
                    sq[reg] = fmaf(v, v, sq[reg]);
                }
            }
#pragma unroll
            for (int reg = 0; reg < 4; ++reg) {
                float s = sq[reg];
                s += __shfl_xor(s, 1);
                s += __shfl_xor(s, 2);
                s += __shfl_xor(s, 4);
                s += __shfl_xor(s, 8);
                if (lr == 0) snorm[wn][wm * 32 + mi * 16 + rbase + reg] = s;
            }
        }
        __syncthreads();
#pragma unroll
        for (int mi = 0; mi < 2; ++mi) {
#pragma unroll
            for (int reg = 0; reg < 4; ++reg) {
                int ridx = wm * 32 + mi * 16 + rbase + reg;
                int r = row0 + ridx;
                float s = snorm[0][ridx] + snorm[1][ridx];
                float inv = 1.0f / fmaxf(sqrtf(s), 1e-12f);
                if (r < nrows) {
#pragma unroll
                    for (int n = 0; n < 8; ++n) {
                        int col = wn * 128 + n * 16 + lr;
                        Cmat[(size_t)r * DIM + col] = fmaxf(acc[mi][n][reg] * inv, 0.f);
                    }
                }
            }
        }
        return;
    }

#pragma unroll
    for (int mi = 0; mi < 2; ++mi) {
#pragma unroll
        for (int reg = 0; reg < 4; ++reg) {
            int r = row0 + wm * 32 + mi * 16 + rbase + reg;
            if (r < nrows) {
#pragma unroll
                for (int n = 0; n < 8; ++n) {
                    int col = wn * 128 + n * 16 + lr;
                    float v = acc[mi][n][reg] + bias[n];
                    if (EPI == 1) v = fmaf(fmaxf(v, 0.f), gm[n], bt[n]);
                    float* cp = &Cmat[(size_t)r * DIM + col];
                    if (EPI == 2) v += *cp;
                    *cp = v;
                }
            }
        }
    }
}

// ---------------- head: MFMA GEMM [n,256]@[256,64(47 used)] + fused log_softmax ----------------
// Block: 64 rows, 4 waves; wave wv handles rows wv*16..+16, all 64 cols (4 frags).
__global__ __launch_bounds__(256) void head_mfma(const float* __restrict__ H,
                                                 const short* __restrict__ Wf,
                                                 const float* __restrict__ b,
                                                 float* __restrict__ out, int nrows) {
    const int tid = threadIdx.x;
    const int lane = tid & 63;
    const int wv = tid >> 6;
    const int row0 = blockIdx.x * 64 + wv * 16;
    const int lr = lane & 15;
    const int lk = (lane >> 4) << 3;

    f32x4 acc[4];
#pragma unroll
    for (int n = 0; n < 4; ++n) acc[n] = (f32x4){0.f, 0.f, 0.f, 0.f};

#pragma unroll
    for (int kt = 0; kt < 8; ++kt) {
        int r = row0 + lr;
        float4 u0 = make_float4(0.f, 0.f, 0.f, 0.f), u1 = u0;
        if (r < nrows) {
            const float* hp = H + (size_t)r * DIM + kt * 32 + lk;
            u0 = ld4(hp);
            u1 = ld4(hp + 4);
        }
        short8 ahi, alo;
        split8(u0, u1, ahi, alo);
        const short* wb = Wf + (((size_t)kt * 4 * 64 + lane) << 3);
#pragma unroll
        for (int n = 0; n < 4; ++n) {
            short8 bhi = *(const short8*)(wb + n * 512);
            short8 blo = *(const short8*)(wb + n * 512 + 16384);
            acc[n] = __builtin_amdgcn_mfma_f32_16x16x32_bf16(ahi, bhi, acc[n], 0, 0, 0);
            acc[n] = __builtin_amdgcn_mfma_f32_16x16x32_bf16(ahi, blo, acc[n], 0, 0, 0);
            acc[n] = __builtin_amdgcn_mfma_f32_16x16x32_bf16(alo, bhi, acc[n], 0, 0, 0);
        }
    }

    // D frag n: col = n*16+lr, row = row0 + (lane>>4)*4 + reg
    float bias[4];
#pragma unroll
    for (int n = 0; n < 4; ++n) {
        int col = n * 16 + lr;
        bias[n] = (col < NCLS) ? b[col] : 0.f;
    }
    const int rbase = (lane >> 4) << 2;
#pragma unroll
    for (int reg = 0; reg < 4; ++reg) {
        float v[4];
        float m = -INFINITY;
#pragma unroll
        for (int n = 0; n < 4; ++n) {
            int col = n * 16 + lr;
            v[n] = (col < NCLS) ? (acc[n][reg] + bias[n]) : -INFINITY;
            m = fmaxf(m, v[n]);
        }
        m = fmaxf(m, __shfl_xor(m, 1));
        m = fmaxf(m, __shfl_xor(m, 2));
        m = fmaxf(m, __shfl_xor(m, 4));
        m = fmaxf(m, __shfl_xor(m, 8));
        float e = 0.f;
#pragma unroll
        for (int n = 0; n < 4; ++n) e += (v[n] > -INFINITY) ? expf(v[n] - m) : 0.f;
        e += __shfl_xor(e, 1);
        e += __shfl_xor(e, 2);
        e += __shfl_xor(e, 4);
        e += __shfl_xor(e, 8);
        float lse = m + logf(e);
        int r = row0 + rbase + reg;
        if (r < nrows) {
#pragma unroll
            for (int n = 0; n < 4; ++n) {
                int col = n * 16 + lr;
                if (col < NCLS) out[(size_t)r * NCLS + col] = v[n] - lse;
            }
        }
    }
}

// ---------------- launch ----------------

extern "C" void kernel_launch(void* const* d_in, const int* in_sizes, int n_in,
                              void* d_out, int out_size, void* d_ws, size_t ws_size,
                              hipStream_t stream) {
    const float* x_in = (const float*)d_in[0];
    const int* ei = (const int*)d_in[1];
    const float* linlW = (const float*)d_in[2];
    const float* linlb = (const float*)d_in[3];
    const float* linrW = (const float*)d_in[4];
    const float* linrb = (const float*)d_in[5];
    const float* W1 = (const float*)d_in[6];
    const float* b1 = (const float*)d_in[7];
    const float* blkWa = (const float*)d_in[8];
    const float* blkba = (const float*)d_in[9];
    const float* blkg = (const float*)d_in[10];
    const float* blkbt = (const float*)d_in[11];
    const float* blkWb = (const float*)d_in[12];
    const float* blkbb = (const float*)d_in[13];
    const float* W2 = (const float*)d_in[14];
    const float* b2 = (const float*)d_in[15];
    const float* pW1 = (const float*)d_in[16];
    const float* pb1 = (const float*)d_in[17];
    const float* pW2 = (const float*)d_in[18];
    const float* pb2 = (const float*)d_in[19];

    const int n = in_sizes[0] / DIM;
    const int E = in_sizes[1] / 2;

    char* ws = (char*)d_ws;
    size_t off = 0;
    auto take = [&](size_t bytes) {
        void* p = ws + off;
        off += (bytes + 255) & ~(size_t)255;
        return p;
    };
    float* bufA = (float*)take((size_t)n * DIM * 4);
    float* bufB = (float*)take((size_t)n * DIM * 4);
    float* bufD = (float*)take((size_t)n * DIM * 4);
    int* cnt = (int*)take((size_t)n * 4);
    int* rowptr = (int*)take((size_t)(n + 1) * 4);
    int* cursor = (int*)take((size_t)n * 4);
    float* invc = (float*)take((size_t)n * 4);
    int* colb = (int*)take((size_t)E * 4);
    short* wbuf = (short*)take((size_t)25 * 131072 * 2);   // 25 DxD matrices hi+lo
    short* w2buf = (short*)take((size_t)32768 * 2);        // head weight frag planes
    (void)ws_size; (void)n_in; (void)out_size;

    const float bnscale = 0.999995000037f;  // 1/sqrt(1 + 1e-5)

    auto WF = [&](int m) { return wbuf + (size_t)m * 131072; };
    // 0..2 linl | 3..5 linr | 6..8 W1 | 9..14 blkWa | 15..20 blkWb | 21..23 W2 | 24 postW1
    conv_w_kernel<<<3 * 32, 256, 0, stream>>>(linlW, WF(0), 3);
    conv_w_kernel<<<3 * 32, 256, 0, stream>>>(linrW, WF(3), 3);
    conv_w_kernel<<<3 * 32, 256, 0, stream>>>(W1, WF(6), 3);
    conv_w_kernel<<<6 * 32, 256, 0, stream>>>(blkWa, WF(9), 6);
    conv_w_kernel<<<6 * 32, 256, 0, stream>>>(blkWb, WF(15), 6);
    conv_w_kernel<<<3 * 32, 256, 0, stream>>>(W2, WF(21), 3);
    conv_w_kernel<<<1 * 32, 256, 0, stream>>>(pW1, WF(24), 1);
    conv_w2_kernel<<<8, 256, 0, stream>>>(pW2, w2buf);

    // CSR build
    hipMemsetAsync(cnt, 0, (size_t)n * 4, stream);
    hist_kernel<<<(E + 255) / 256, 256, 0, stream>>>(ei, cnt, E);
    scan_kernel<<<1, 1024, 0, stream>>>(cnt, rowptr, cursor, invc, n);
    fill_kernel<<<(E + 255) / 256, 256, 0, stream>>>(ei, cursor, colb, E);

    const int gblocks = (n + 63) / 64;
    const float* xcur = x_in;
    for (int i = 0; i < NL; ++i) {
        gather_mean<<<(n + 3) / 4, 256, 0, stream>>>(xcur, rowptr, colb, invc, bufB, n);
        gemm_mfma<0, true><<<gblocks, 256, 0, stream>>>(
            xcur, WF(0 + i), bufB, WF(3 + i),
            linlb + i * 256, linrb + i * 256, nullptr, nullptr, 0.f, bufB, n);
        gemm_mfma<0, false><<<gblocks, 256, 0, stream>>>(
            bufB, WF(6 + i), nullptr, nullptr, b1 + i * 256, nullptr,
            nullptr, nullptr, 0.f, bufD, n);
        for (int j = 0; j < 2; ++j) {
            int wo = i * 2 + j;
            gemm_mfma<1, false><<<gblocks, 256, 0, stream>>>(
                bufD, WF(9 + wo), nullptr, nullptr, blkba + wo * 256, nullptr,
                blkg + wo * 256, blkbt + wo * 256, bnscale, bufB, n);
            gemm_mfma<2, false><<<gblocks, 256, 0, stream>>>(
                bufB, WF(15 + wo), nullptr, nullptr, blkbb + wo * 256, nullptr,
                nullptr, nullptr, 0.f, bufD, n);
        }
        gemm_mfma<3, false><<<gblocks, 256, 0, stream>>>(
            bufD, WF(21 + i), nullptr, nullptr, b2 + i * 256, nullptr,
            nullptr, nullptr, 0.f, bufA, n);
        xcur = bufA;
    }
    gemm_mfma<0, false><<<gblocks, 256, 0, stream>>>(
        bufA, WF(24), nullptr, nullptr, pb1, nullptr, nullptr, nullptr, 0.f, bufB, n);
    head_mfma<<<gblocks, 256, 0, stream>>>(bufB, w2buf, pb2, (float*)d_out, n);
}

// Round 4
// 1576.775 us; speedup vs baseline: 2.2751x; 1.2814x over previous
//
#include <hip/hip_runtime.h>
#include <hip/hip_bf16.h>
#include <math.h>

// ResidualMP GNN inference. Layer-fused MFMA (split bf16 hi/lo ~fp32 accuracy).
// N=50000, E=800000, D=MH=256, C=47, L=3.
// Per layer ONE kernel: 64-row block carries prop->h->(t,h+=)x2->l2norm through
// LDS (XOR-swizzled [64][256] f32 tile); h persists in VGPRs for the residual.

constexpr int DIM = 256;
constexpr int NCLS = 47;

typedef short short8 __attribute__((ext_vector_type(8)));
typedef float f32x4 __attribute__((ext_vector_type(4)));

__device__ __forceinline__ float4 ld4(const float* p) { return *(const float4*)p; }

// scalar split (conversion kernels only)
__device__ __forceinline__ void split_bf16(float a, short& hi, short& lo) {
    unsigned u = __float_as_uint(a);
    unsigned r = (u + 0x7fffu + ((u >> 16) & 1u)) & 0xffff0000u;
    hi = (short)(r >> 16);
    float f = a - __uint_as_float(r);   // exact (Sterbenz)
    unsigned u2 = __float_as_uint(f);
    lo = (short)((u2 + 0x7fffu + ((u2 >> 16) & 1u)) >> 16);
}

// fast 8-wide split: v_cvt_pk_bf16_f32 pairs, residual exact
__device__ __forceinline__ void split8(const float4& u0, const float4& u1,
                                       short8& hi, short8& lo) {
    union { unsigned w[4]; short8 s; } H, L;
    float va[8] = {u0.x, u0.y, u0.z, u0.w, u1.x, u1.y, u1.z, u1.w};
#pragma unroll
    for (int p = 0; p < 4; ++p) {
        float a = va[2 * p], b = va[2 * p + 1];
        __hip_bfloat162 h2 = __float22bfloat162_rn(make_float2(a, b));
        float ra = a - __bfloat162float(h2.x);
        float rb = b - __bfloat162float(h2.y);
        __hip_bfloat162 l2 = __float22bfloat162_rn(make_float2(ra, rb));
        H.w[p] = *reinterpret_cast<unsigned*>(&h2);
        L.w[p] = *reinterpret_cast<unsigned*>(&l2);
    }
    hi = H.s; lo = L.s;
}

// XOR-swizzled address into a [64][256] f32 LDS tile (16B-chunk granular).
// Breaks the 16-way bank conflict of row-stride-256 fragment reads -> 2-way.
__device__ __forceinline__ int swz(int r, int c) {
    return (r << 8) + (((((c >> 2) ^ (r & 7)) & 63) << 2) | (c & 3));
}

// ---------------- CSR build ----------------

__global__ void hist_kernel(const int* __restrict__ ei, int* __restrict__ cnt, int E) {
    int g = blockIdx.x * blockDim.x + threadIdx.x;
    if (g < E) atomicAdd(&cnt[ei[E + g]], 1);   // dst = ei[1][e]
}

__global__ __launch_bounds__(256) void scan_part(const int* __restrict__ cnt,
                                                 int* __restrict__ bsum, int n) {
    int t = threadIdx.x;
    int i0 = blockIdx.x * 1024 + t * 4;
    int4 v = make_int4(0, 0, 0, 0);
    if (i0 + 3 < n) v = *(const int4*)&cnt[i0];
    else {
        if (i0 < n) v.x = cnt[i0];
        if (i0 + 1 < n) v.y = cnt[i0 + 1];
        if (i0 + 2 < n) v.z = cnt[i0 + 2];
        if (i0 + 3 < n) v.w = cnt[i0 + 3];
    }
    int s = v.x + v.y + v.z + v.w;
#pragma unroll
    for (int off = 1; off < 64; off <<= 1) s += __shfl_xor(s, off);
    __shared__ int ws[4];
    if ((t & 63) == 0) ws[t >> 6] = s;
    __syncthreads();
    if (t == 0) bsum[blockIdx.x] = ws[0] + ws[1] + ws[2] + ws[3];
}

__global__ void scan_bsum(int* __restrict__ bsum, int nb) {  // 1 block, 64 threads
    int lane = threadIdx.x;
    int orig = (lane < nb) ? bsum[lane] : 0;
    int incl = orig;
#pragma unroll
    for (int off = 1; off < 64; off <<= 1) {
        int u = __shfl_up(incl, off);
        if (lane >= off) incl += u;
    }
    if (lane < nb) bsum[lane] = incl - orig;  // exclusive
}

__global__ __launch_bounds__(256) void scan_final(const int* __restrict__ cnt,
                                                  const int* __restrict__ bsum,
                                                  int* __restrict__ rowptr,
                                                  int* __restrict__ cursor,
                                                  float* __restrict__ invc, int n, int E) {
    int t = threadIdx.x;
    int lane = t & 63, wv = t >> 6;
    int i0 = blockIdx.x * 1024 + t * 4;
    int4 v = make_int4(0, 0, 0, 0);
    if (i0 + 3 < n) v = *(const int4*)&cnt[i0];
    else {
        if (i0 < n) v.x = cnt[i0];
        if (i0 + 1 < n) v.y = cnt[i0 + 1];
        if (i0 + 2 < n) v.z = cnt[i0 + 2];
        if (i0 + 3 < n) v.w = cnt[i0 + 3];
    }
    int s = v.x + v.y + v.z + v.w;
    int incl = s;
#pragma unroll
    for (int off = 1; off < 64; off <<= 1) {
        int u = __shfl_up(incl, off);
        if (lane >= off) incl += u;
    }
    __shared__ int wtot[4];
    if (lane == 63) wtot[wv] = incl;
    __syncthreads();
    int woff = 0;
    for (int w = 0; w < 4; ++w) woff += (w < wv) ? wtot[w] : 0;
    int p = bsum[blockIdx.x] + woff + incl - s;
    int vv[4] = {v.x, v.y, v.z, v.w};
#pragma unroll
    for (int j = 0; j < 4; ++j) {
        int i = i0 + j;
        if (i < n) {
            rowptr[i] = p;
            cursor[i] = p;
            int c = vv[j];
            invc[i] = 1.0f / (float)(c > 0 ? c : 1);
            p += c;
        }
    }
    if (blockIdx.x == 0 && t == 0) rowptr[n] = E;
}

__global__ void fill_kernel(const int* __restrict__ ei, int* __restrict__ cursor,
                            int* __restrict__ colb, int E) {
    int g = blockIdx.x * blockDim.x + threadIdx.x;
    if (g < E) {
        int s = ei[g];
        int d = ei[E + g];
        int p = atomicAdd(&cursor[d], 1);
        colb[p] = s;
    }
}

// one wave per destination row: z[r] = (1/max(deg,1)) * sum_p x[col[p]]
__global__ __launch_bounds__(256) void gather_mean(const float* __restrict__ x,
                                                   const int* __restrict__ rowptr,
                                                   const int* __restrict__ colb,
                                                   const float* __restrict__ invc,
                                                   float* __restrict__ z, int n) {
    int gw = (blockIdx.x * 256 + threadIdx.x) >> 6;
    int lane = threadIdx.x & 63;
    int nw = (gridDim.x * 256) >> 6;
    for (int r = gw; r < n; r += nw) {
        int p0 = rowptr[r], p1 = rowptr[r + 1];
        float a0 = 0.f, a1 = 0.f, a2 = 0.f, a3 = 0.f;
        for (int p = p0; p < p1; ++p) {
            int s = colb[p];
            float4 v = ld4(&x[(size_t)s * DIM + lane * 4]);
            a0 += v.x; a1 += v.y; a2 += v.z; a3 += v.w;
        }
        float iv = invc[r];
        *(float4*)&z[(size_t)r * DIM + lane * 4] = make_float4(a0 * iv, a1 * iv, a2 * iv, a3 * iv);
    }
}

// ---------------- weight conversion: fp32 [256][256] -> frag-ordered hi/lo bf16 ----------------
// Entry e=(kt*16+ct)*64+lane holds B[k=kt*32+(lane>>4)*8+j][col=ct*16+(lane&15)], j=0..7.
__global__ __launch_bounds__(256) void conv_w_kernel(const float* __restrict__ W,
                                                     short* __restrict__ out, int nmat) {
    int idx = blockIdx.x * 256 + threadIdx.x;
    if (idx >= nmat * 8192) return;
    int m = idx >> 13;
    int e = idx & 8191;
    int kt = e >> 10;
    int ct = (e >> 6) & 15;
    int lane = e & 63;
    int k0 = kt * 32 + ((lane >> 4) << 3);
    int col = ct * 16 + (lane & 15);
    const float* Wm = W + (size_t)m * 65536;
    short8 hi, lo;
#pragma unroll
    for (int j = 0; j < 8; ++j) {
        short h, l;
        split_bf16(Wm[(size_t)(k0 + j) * 256 + col], h, l);
        hi[j] = h; lo[j] = l;
    }
    short* hp = out + (size_t)m * 131072 + (size_t)e * 8;
    *(short8*)hp = hi;
    *(short8*)(hp + 65536) = lo;
}

// post_W2 [256][47] -> frag planes padded to 64 cols: 8 kt x 4 ct x 64 lanes.
__global__ __launch_bounds__(256) void conv_w2_kernel(const float* __restrict__ W,
                                                      short* __restrict__ out) {
    int e = blockIdx.x * 256 + threadIdx.x;
    if (e >= 2048) return;
    int kt = e >> 8;
    int ct = (e >> 6) & 3;
    int lane = e & 63;
    int k0 = kt * 32 + ((lane >> 4) << 3);
    int col = ct * 16 + (lane & 15);
    short8 hi, lo;
#pragma unroll
    for (int j = 0; j < 8; ++j) {
        float v = (col < NCLS) ? W[(size_t)(k0 + j) * NCLS + col] : 0.f;
        short h, l;
        split_bf16(v, h, l);
        hi[j] = h; lo[j] = l;
    }
    short* hp = out + (size_t)e * 8;
    *(short8*)hp = hi;
    *(short8*)(hp + 16384) = lo;
}

// ---------------- MFMA passes (acc += A@W, split bf16 hi/lo, 3 MFMA per frag) ----------------

__device__ __forceinline__ void mma_global(f32x4 (&acc)[2][8], const float* __restrict__ A,
                                           const short* __restrict__ Wf,
                                           int row0, int nrows, int wm, int wn, int lane) {
    const int lr = lane & 15;
    const int lk = (lane >> 4) << 3;
#pragma unroll
    for (int kt = 0; kt < 8; ++kt) {
        short8 ahi[2], alo[2];
#pragma unroll
        for (int mi = 0; mi < 2; ++mi) {
            int r = row0 + wm * 32 + mi * 16 + lr;
            float4 u0 = make_float4(0.f, 0.f, 0.f, 0.f), u1 = u0;
            if (r < nrows) {
                const float* ap = A + (size_t)r * DIM + kt * 32 + lk;
                u0 = ld4(ap);
                u1 = ld4(ap + 4);
            }
            split8(u0, u1, ahi[mi], alo[mi]);
        }
        const short* wb = Wf + (((size_t)(kt * 16 + wn * 8) * 64 + lane) << 3);
#pragma unroll
        for (int n = 0; n < 8; ++n) {
            short8 bhi = *(const short8*)(wb + n * 512);
            short8 blo = *(const short8*)(wb + n * 512 + 65536);
#pragma unroll
            for (int mi = 0; mi < 2; ++mi) {
                acc[mi][n] = __builtin_amdgcn_mfma_f32_16x16x32_bf16(ahi[mi], bhi, acc[mi][n], 0, 0, 0);
                acc[mi][n] = __builtin_amdgcn_mfma_f32_16x16x32_bf16(ahi[mi], blo, acc[mi][n], 0, 0, 0);
                acc[mi][n] = __builtin_amdgcn_mfma_f32_16x16x32_bf16(alo[mi], bhi, acc[mi][n], 0, 0, 0);
            }
        }
    }
}

__device__ __forceinline__ void mma_lds(f32x4 (&acc)[2][8], const float* sAf,
                                        const short* __restrict__ Wf,
                                        int wm, int wn, int lane) {
    const int lr = lane & 15;
    const int lk = (lane >> 4) << 3;
#pragma unroll
    for (int kt = 0; kt < 8; ++kt) {
        short8 ahi[2], alo[2];
#pragma unroll
        for (int mi = 0; mi < 2; ++mi) {
            int r = wm * 32 + mi * 16 + lr;
            int k0 = kt * 32 + lk;
            const float* ap0 = sAf + (r << 8) + ((((k0 >> 2) ^ (r & 7)) & 63) << 2);
            const float* ap1 = sAf + (r << 8) + (((((k0 + 4) >> 2) ^ (r & 7)) & 63) << 2);
            float4 u0 = *(const float4*)ap0;
            float4 u1 = *(const float4*)ap1;
            split8(u0, u1, ahi[mi], alo[mi]);
        }
        const short* wb = Wf + (((size_t)(kt * 16 + wn * 8) * 64 + lane) << 3);
#pragma unroll
        for (int n = 0; n < 8; ++n) {
            short8 bhi = *(const short8*)(wb + n * 512);
            short8 blo = *(const short8*)(wb + n * 512 + 65536);
#pragma unroll
            for (int mi = 0; mi < 2; ++mi) {
                acc[mi][n] = __builtin_amdgcn_mfma_f32_16x16x32_bf16(ahi[mi], bhi, acc[mi][n], 0, 0, 0);
                acc[mi][n] = __builtin_amdgcn_mfma_f32_16x16x32_bf16(ahi[mi], blo, acc[mi][n], 0, 0, 0);
                acc[mi][n] = __builtin_amdgcn_mfma_f32_16x16x32_bf16(alo[mi], bhi, acc[mi][n], 0, 0, 0);
            }
        }
    }
}

// ---------------- fused layer kernel ----------------
// Stages: S0 prop = x@Wll + z@Wlr + biases        (global A, dual)
//         S1 h    = prop@W1 + b1                  (hreg := h)
//         S2 t    = g*bn*relu(h@Wa0 + ba0) + be0
//         S3 h   += t@Wb0 + bb0                   (hreg := h)
//         S4/S5 same with a1/b1
//         S6 x'   = relu(l2norm(h@W2 + b2))       -> global
__global__ __launch_bounds__(256, 2) void layer_fused(
    const float* __restrict__ xin, const float* __restrict__ zin,
    const short* __restrict__ Wll, const short* __restrict__ Wlr,
    const short* __restrict__ Wm1,
    const short* __restrict__ Wa0, const short* __restrict__ Wb0f,
    const short* __restrict__ Wa1, const short* __restrict__ Wb1f,
    const short* __restrict__ Wm2,
    const float* __restrict__ b_ll, const float* __restrict__ b_lr,
    const float* __restrict__ b_m1,
    const float* __restrict__ b_a0, const float* __restrict__ gam0,
    const float* __restrict__ bet0, const float* __restrict__ b_b0,
    const float* __restrict__ b_a1, const float* __restrict__ gam1,
    const float* __restrict__ bet1, const float* __restrict__ b_b1,
    const float* __restrict__ b_m2,
    float bnscale, float* __restrict__ xout, int nrows) {
    __shared__ float sAf[64 * 256];
    const int tid = threadIdx.x;
    const int lane = tid & 63;
    const int wv = tid >> 6;
    const int wm = wv & 1;
    const int wn = wv >> 1;
    const int row0 = blockIdx.x * 64;
    const int lr = lane & 15;
    const int rbase = (lane >> 4) << 2;

    f32x4 acc[2][8];
    float hreg[2][8][4];

    auto zeroacc = [&]() {
#pragma unroll
        for (int mi = 0; mi < 2; ++mi)
#pragma unroll
            for (int n = 0; n < 8; ++n) acc[mi][n] = (f32x4){0.f, 0.f, 0.f, 0.f};
    };
    auto store = [&](auto f) {
        __syncthreads();  // all waves done reading previous LDS contents
#pragma unroll
        for (int mi = 0; mi < 2; ++mi)
#pragma unroll
            for (int reg = 0; reg < 4; ++reg) {
                int r = wm * 32 + mi * 16 + rbase + reg;
#pragma unroll
                for (int n = 0; n < 8; ++n)
                    sAf[swz(r, wn * 128 + n * 16 + lr)] = f(mi, n, reg);
            }
        __syncthreads();
    };

    // ---- S0 ----
    zeroacc();
    mma_global(acc, xin, Wll, row0, nrows, wm, wn, lane);
    mma_global(acc, zin, Wlr, row0, nrows, wm, wn, lane);
    {
        float bias[8];
#pragma unroll
        for (int n = 0; n < 8; ++n) {
            int c = wn * 128 + n * 16 + lr;
            bias[n] = b_ll[c] + b_lr[c];
        }
        store([&](int mi, int n, int reg) { return acc[mi][n][reg] + bias[n]; });
    }
    // ---- S1 ----
    zeroacc();
    mma_lds(acc, sAf, Wm1, wm, wn, lane);
    {
        float bias[8];
#pragma unroll
        for (int n = 0; n < 8; ++n) bias[n] = b_m1[wn * 128 + n * 16 + lr];
        store([&](int mi, int n, int reg) {
            float v = acc[mi][n][reg] + bias[n];
            hreg[mi][n][reg] = v;
            return v;
        });
    }
    // ---- ResNet blocks ----
    const short* Was[2] = {Wa0, Wa1};
    const short* Wbs[2] = {Wb0f, Wb1f};
    const float* bas[2] = {b_a0, b_a1};
    const float* gms[2] = {gam0, gam1};
    const float* bes[2] = {bet0, bet1};
    const float* bbs[2] = {b_b0, b_b1};
    for (int j = 0; j < 2; ++j) {
        zeroacc();
        mma_lds(acc, sAf, Was[j], wm, wn, lane);
        {
            float ba[8], gm[8], be[8];
#pragma unroll
            for (int n = 0; n < 8; ++n) {
                int c = wn * 128 + n * 16 + lr;
                ba[n] = bas[j][c];
                gm[n] = gms[j][c] * bnscale;
                be[n] = bes[j][c];
            }
            store([&](int mi, int n, int reg) {
                return fmaf(fmaxf(acc[mi][n][reg] + ba[n], 0.f), gm[n], be[n]);
            });
        }
        zeroacc();
        mma_lds(acc, sAf, Wbs[j], wm, wn, lane);
        {
            float bb[8];
#pragma unroll
            for (int n = 0; n < 8; ++n) bb[n] = bbs[j][wn * 128 + n * 16 + lr];
            store([&](int mi, int n, int reg) {
                float v = hreg[mi][n][reg] + acc[mi][n][reg] + bb[n];
                hreg[mi][n][reg] = v;
                return v;
            });
        }
    }
    // ---- S6: o = h@W2 + b2 ; x' = relu(o / max(||o||,1e-12)) ----
    zeroacc();
    mma_lds(acc, sAf, Wm2, wm, wn, lane);
    {
        float bias[8];
#pragma unroll
        for (int n = 0; n < 8; ++n) bias[n] = b_m2[wn * 128 + n * 16 + lr];
        float sqs[2][4];
#pragma unroll
        for (int mi = 0; mi < 2; ++mi) {
            float sq[4] = {0.f, 0.f, 0.f, 0.f};
#pragma unroll
            for (int n = 0; n < 8; ++n)
#pragma unroll
                for (int reg = 0; reg < 4; ++reg) {
                    float v = acc[mi][n][reg] + bias[n];
                    acc[mi][n][reg] = v;
                    sq[reg] = fmaf(v, v, sq[reg]);
                }
#pragma unroll
            for (int reg = 0; reg < 4; ++reg) {
                float s = sq[reg];
                s += __shfl_xor(s, 1);
                s += __shfl_xor(s, 2);
                s += __shfl_xor(s, 4);
                s += __shfl_xor(s, 8);
                sqs[mi][reg] = s;
            }
        }
        __syncthreads();  // all waves done reading sAf -> reuse first 128 floats
        float* sn = sAf;
        if (lr == 0) {
#pragma unroll
            for (int mi = 0; mi < 2; ++mi)
#pragma unroll
                for (int reg = 0; reg < 4; ++reg)
                    sn[wn * 64 + wm * 32 + mi * 16 + rbase + reg] = sqs[mi][reg];
        }
        __syncthreads();
#pragma unroll
        for (int mi = 0; mi < 2; ++mi)
#pragma unroll
            for (int reg = 0; reg < 4; ++reg) {
                int ridx = wm * 32 + mi * 16 + rbase + reg;
                int r = row0 + ridx;
                float s = sn[ridx] + sn[64 + ridx];
                float inv = 1.0f / fmaxf(sqrtf(s), 1e-12f);
                if (r < nrows) {
#pragma unroll
                    for (int n = 0; n < 8; ++n) {
                        int col = wn * 128 + n * 16 + lr;
                        xout[(size_t)r * DIM + col] = fmaxf(acc[mi][n][reg] * inv, 0.f);
                    }
                }
            }
    }
}

// ---------------- fused post-MLP + head + log_softmax ----------------
__global__ __launch_bounds__(256, 2) void post_head(
    const float* __restrict__ xin, const short* __restrict__ WpF,
    const float* __restrict__ pb1, const short* __restrict__ W2f,
    const float* __restrict__ pb2, float* __restrict__ out, int nrows) {
    __shared__ float sAf[64 * 256];
    const int tid = threadIdx.x;
    const int lane = tid & 63;
    const int wv = tid >> 6;
    const int wm = wv & 1;
    const int wn = wv >> 1;
    const int row0 = blockIdx.x * 64;
    const int lr = lane & 15;
    const int lk = (lane >> 4) << 3;
    const int rbase = (lane >> 4) << 2;

    f32x4 acc[2][8];
#pragma unroll
    for (int mi = 0; mi < 2; ++mi)
#pragma unroll
        for (int n = 0; n < 8; ++n) acc[mi][n] = (f32x4){0.f, 0.f, 0.f, 0.f};
    mma_global(acc, xin, WpF, row0, nrows, wm, wn, lane);
    {
        float bias[8];
#pragma unroll
        for (int n = 0; n < 8; ++n) bias[n] = pb1[wn * 128 + n * 16 + lr];
        __syncthreads();
#pragma unroll
        for (int mi = 0; mi < 2; ++mi)
#pragma unroll
            for (int reg = 0; reg < 4; ++reg) {
                int r = wm * 32 + mi * 16 + rbase + reg;
#pragma unroll
                for (int n = 0; n < 8; ++n)
                    sAf[swz(r, wn * 128 + n * 16 + lr)] = acc[mi][n][reg] + bias[n];
            }
        __syncthreads();
    }
    // head: wave wv owns rows wv*16..+16, 4 col-frags (64 cols, 47 used)
    f32x4 hacc[4];
#pragma unroll
    for (int n = 0; n < 4; ++n) hacc[n] = (f32x4){0.f, 0.f, 0.f, 0.f};
#pragma unroll
    for (int kt = 0; kt < 8; ++kt) {
        int r = wv * 16 + lr;
        int k0 = kt * 32 + lk;
        const float* ap0 = sAf + (r << 8) + ((((k0 >> 2) ^ (r & 7)) & 63) << 2);
        const float* ap1 = sAf + (r << 8) + (((((k0 + 4) >> 2) ^ (r & 7)) & 63) << 2);
        float4 u0 = *(const float4*)ap0;
        float4 u1 = *(const float4*)ap1;
        short8 ahi, alo;
        split8(u0, u1, ahi, alo);
        const short* wb = W2f + (((size_t)kt * 4 * 64 + lane) << 3);
#pragma unroll
        for (int n = 0; n < 4; ++n) {
            short8 bhi = *(const short8*)(wb + n * 512);
            short8 blo = *(const short8*)(wb + n * 512 + 16384);
            hacc[n] = __builtin_amdgcn_mfma_f32_16x16x32_bf16(ahi, bhi, hacc[n], 0, 0, 0);
            hacc[n] = __builtin_amdgcn_mfma_f32_16x16x32_bf16(ahi, blo, hacc[n], 0, 0, 0);
            hacc[n] = __builtin_amdgcn_mfma_f32_16x16x32_bf16(alo, bhi, hacc[n], 0, 0, 0);
        }
    }
    float bias[4];
#pragma unroll
    for (int n = 0; n < 4; ++n) {
        int col = n * 16 + lr;
        bias[n] = (col < NCLS) ? pb2[col] : 0.f;
    }
#pragma unroll
    for (int reg = 0; reg < 4; ++reg) {
        float v[4];
        float m = -INFINITY;
#pragma unroll
        for (int n = 0; n < 4; ++n) {
            int col = n * 16 + lr;
            v[n] = (col < NCLS) ? (hacc[n][reg] + bias[n]) : -INFINITY;
            m = fmaxf(m, v[n]);
        }
        m = fmaxf(m, __shfl_xor(m, 1));
        m = fmaxf(m, __shfl_xor(m, 2));
        m = fmaxf(m, __shfl_xor(m, 4));
        m = fmaxf(m, __shfl_xor(m, 8));
        float e = 0.f;
#pragma unroll
        for (int n = 0; n < 4; ++n) e += (v[n] > -INFINITY) ? expf(v[n] - m) : 0.f;
        e += __shfl_xor(e, 1);
        e += __shfl_xor(e, 2);
        e += __shfl_xor(e, 4);
        e += __shfl_xor(e, 8);
        float lse = m + logf(e);
        int r = row0 + wv * 16 + rbase + reg;
        if (r < nrows) {
#pragma unroll
            for (int n = 0; n < 4; ++n) {
                int col = n * 16 + lr;
                if (col < NCLS) out[(size_t)r * NCLS + col] = v[n] - lse;
            }
        }
    }
}

// ---------------- launch ----------------

extern "C" void kernel_launch(void* const* d_in, const int* in_sizes, int n_in,
                              void* d_out, int out_size, void* d_ws, size_t ws_size,
                              hipStream_t stream) {
    const float* x_in = (const float*)d_in[0];
    const int* ei = (const int*)d_in[1];
    const float* linlW = (const float*)d_in[2];
    const float* linlb = (const float*)d_in[3];
    const float* linrW = (const float*)d_in[4];
    const float* linrb = (const float*)d_in[5];
    const float* W1 = (const float*)d_in[6];
    const float* b1 = (const float*)d_in[7];
    const float* blkWa = (const float*)d_in[8];
    const float* blkba = (const float*)d_in[9];
    const float* blkg = (const float*)d_in[10];
    const float* blkbt = (const float*)d_in[11];
    const float* blkWb = (const float*)d_in[12];
    const float* blkbb = (const float*)d_in[13];
    const float* W2 = (const float*)d_in[14];
    const float* b2 = (const float*)d_in[15];
    const float* pW1 = (const float*)d_in[16];
    const float* pb1 = (const float*)d_in[17];
    const float* pW2 = (const float*)d_in[18];
    const float* pb2 = (const float*)d_in[19];

    const int n = in_sizes[0] / DIM;
    const int E = in_sizes[1] / 2;

    char* ws = (char*)d_ws;
    size_t off = 0;
    auto take = [&](size_t bytes) {
        void* p = ws + off;
        off += (bytes + 255) & ~(size_t)255;
        return p;
    };
    float* bufA = (float*)take((size_t)n * DIM * 4);
    float* bufD = (float*)take((size_t)n * DIM * 4);
    float* bufZ = (float*)take((size_t)n * DIM * 4);
    int* cnt = (int*)take((size_t)n * 4);
    int* rowptr = (int*)take((size_t)(n + 1) * 4);
    int* cursor = (int*)take((size_t)n * 4);
    float* invc = (float*)take((size_t)n * 4);
    int* colb = (int*)take((size_t)E * 4);
    int* bsum = (int*)take(256 * 4);
    short* wbuf = (short*)take((size_t)25 * 131072 * 2);
    short* w2buf = (short*)take((size_t)32768 * 2);
    (void)ws_size; (void)n_in; (void)out_size;

    const float bnscale = 0.999995000037f;  // 1/sqrt(1 + 1e-5)

    auto WF = [&](int m) { return wbuf + (size_t)m * 131072; };
    // 0..2 linl | 3..5 linr | 6..8 W1 | 9..14 blkWa | 15..20 blkWb | 21..23 W2 | 24 postW1
    conv_w_kernel<<<3 * 32, 256, 0, stream>>>(linlW, WF(0), 3);
    conv_w_kernel<<<3 * 32, 256, 0, stream>>>(linrW, WF(3), 3);
    conv_w_kernel<<<3 * 32, 256, 0, stream>>>(W1, WF(6), 3);
    conv_w_kernel<<<6 * 32, 256, 0, stream>>>(blkWa, WF(9), 6);
    conv_w_kernel<<<6 * 32, 256, 0, stream>>>(blkWb, WF(15), 6);
    conv_w_kernel<<<3 * 32, 256, 0, stream>>>(W2, WF(21), 3);
    conv_w_kernel<<<1 * 32, 256, 0, stream>>>(pW1, WF(24), 1);
    conv_w2_kernel<<<8, 256, 0, stream>>>(pW2, w2buf);

    // CSR build (parallel scan)
    hipMemsetAsync(cnt, 0, (size_t)n * 4, stream);
    hist_kernel<<<(E + 255) / 256, 256, 0, stream>>>(ei, cnt, E);
    const int nb = (n + 1023) / 1024;
    scan_part<<<nb, 256, 0, stream>>>(cnt, bsum, n);
    scan_bsum<<<1, 64, 0, stream>>>(bsum, nb);
    scan_final<<<nb, 256, 0, stream>>>(cnt, bsum, rowptr, cursor, invc, n, E);
    fill_kernel<<<(E + 255) / 256, 256, 0, stream>>>(ei, cursor, colb, E);

    const int gblocks = (n + 63) / 64;
    const float* xcur = x_in;
    float* xbufs[2] = {bufA, bufD};
    for (int i = 0; i < 3; ++i) {
        gather_mean<<<(n + 3) / 4, 256, 0, stream>>>(xcur, rowptr, colb, invc, bufZ, n);
        int wo = i * 2;
        float* xo = xbufs[i & 1];
        layer_fused<<<gblocks, 256, 0, stream>>>(
            xcur, bufZ,
            WF(0 + i), WF(3 + i), WF(6 + i),
            WF(9 + wo), WF(15 + wo), WF(9 + wo + 1), WF(15 + wo + 1),
            WF(21 + i),
            linlb + i * 256, linrb + i * 256, b1 + i * 256,
            blkba + wo * 256, blkg + wo * 256, blkbt + wo * 256, blkbb + wo * 256,
            blkba + (wo + 1) * 256, blkg + (wo + 1) * 256, blkbt + (wo + 1) * 256,
            blkbb + (wo + 1) * 256,
            b2 + i * 256, bnscale, xo, n);
        xcur = xo;
    }
    post_head<<<gblocks, 256, 0, stream>>>(xcur, WF(24), pb1, w2buf, pb2, (float*)d_out, n);
}